// Round 1
// baseline (344.693 us; speedup 1.0000x reference)
//
#include <hip/hip_runtime.h>
#include <stdint.h>
#include <math.h>

#define NH 16
#define DH 64
#define SEQ 2048
#define NB 2
#define DMODEL 1024

typedef short short8 __attribute__((ext_vector_type(8)));
typedef short short4v __attribute__((ext_vector_type(4)));
typedef float f32x4 __attribute__((ext_vector_type(4)));

__device__ __forceinline__ short f2bf(float f) {
  union { float f; uint32_t u; } c; c.f = f;
  uint32_t u = c.u;
  uint32_t r = (u + 0x7FFFu + ((u >> 16) & 1u)) >> 16;
  return (short)(r & 0xFFFFu);
}

// ---------------- convert x (fp32 -> bf16), 4 elems/thread ----------------
__global__ void k_convert_x(const float* __restrict__ x, short* __restrict__ xb) {
  int i = blockIdx.x * blockDim.x + threadIdx.x;
  f32x4 v = ((const f32x4*)x)[i];
  short4v o;
  o[0] = f2bf(v[0]); o[1] = f2bf(v[1]); o[2] = f2bf(v[2]); o[3] = f2bf(v[3]);
  ((short4v*)xb)[i] = o;
}

// ------------- transpose+convert: in[R][C] fp32 -> out[C][R] bf16 ----------
__global__ void k_transpose_bf16(const float* __restrict__ in, short* __restrict__ out,
                                 int R, int C) {
  __shared__ float tile[32][33];
  int tx = threadIdx.x, ty = threadIdx.y;
  int c0 = blockIdx.x * 32, r0 = blockIdx.y * 32;
#pragma unroll
  for (int i = 0; i < 4; ++i)
    tile[ty + i * 8][tx] = in[(size_t)(r0 + ty + i * 8) * C + c0 + tx];
  __syncthreads();
#pragma unroll
  for (int i = 0; i < 4; ++i)
    out[(size_t)(c0 + ty + i * 8) * R + r0 + tx] = f2bf(tile[tx][ty + i * 8]);
}

// ---------------- GEMM: C[M,N] = A[M,K=1024] * Bt[N,K]^T + bias ------------
// MODE 0: scatter bf16 into q/k/v [B,H,L,dh]   MODE 1: fp32 out [M,1024]
template <int MODE>
__launch_bounds__(256)
__global__ void k_gemm(const short* __restrict__ A, const short* __restrict__ Bt,
                       const float* __restrict__ bias, float* __restrict__ Cf,
                       short* __restrict__ qo, short* __restrict__ ko,
                       short* __restrict__ vo) {
  constexpr int KD = 1024;
  constexpr int ST = 40;  // padded LDS row stride (shorts): 2-way bank alias = free
  __shared__ __align__(16) short As[128 * ST];
  __shared__ __align__(16) short Bs[128 * ST];
  const int tid = threadIdx.x;
  const int wave = tid >> 6, lane = tid & 63;
  const int quad = lane >> 4, l16 = lane & 15;
  const int wm = wave >> 1, wn = wave & 1;
  const int tM = blockIdx.y * 128, tN = blockIdx.x * 128;

  f32x4 acc[4][4] = {};

  for (int k0 = 0; k0 < KD; k0 += 32) {
    __syncthreads();
#pragma unroll
    for (int p = 0; p < 2; ++p) {
      int c = p * 256 + tid;
      int row = c >> 2, col = (c & 3) * 8;
      *(short8*)&As[row * ST + col] =
          *(const short8*)&A[(size_t)(tM + row) * KD + k0 + col];
      *(short8*)&Bs[row * ST + col] =
          *(const short8*)&Bt[(size_t)(tN + row) * KD + k0 + col];
    }
    __syncthreads();
    short8 af[4], bfr[4];
#pragma unroll
    for (int i = 0; i < 4; ++i)
      af[i] = *(const short8*)&As[(wm * 64 + i * 16 + l16) * ST + quad * 8];
#pragma unroll
    for (int i = 0; i < 4; ++i)
      bfr[i] = *(const short8*)&Bs[(wn * 64 + i * 16 + l16) * ST + quad * 8];
#pragma unroll
    for (int i = 0; i < 4; ++i)
#pragma unroll
      for (int j = 0; j < 4; ++j)
        acc[i][j] = __builtin_amdgcn_mfma_f32_16x16x32_bf16(af[i], bfr[j], acc[i][j], 0, 0, 0);
  }

  const int rbase = tM + wm * 64 + quad * 4;
#pragma unroll
  for (int i = 0; i < 4; ++i) {
#pragma unroll
    for (int j = 0; j < 4; ++j) {
      const int col = tN + wn * 64 + j * 16 + l16;
      const float bi = bias[col];
      if (MODE == 0) {
        const int which = col >> 10;
        const int h = (col & 1023) >> 6, d = col & 63;
        short* dst = (which == 0) ? qo : (which == 1) ? ko : vo;
#pragma unroll
        for (int rr = 0; rr < 4; ++rr) {
          const int row = rbase + i * 16 + rr;
          const int b = row >> 11, li = row & 2047;
          dst[(((size_t)(b * NH + h)) * SEQ + li) * DH + d] = f2bf(acc[i][j][rr] + bi);
        }
      } else {
#pragma unroll
        for (int rr = 0; rr < 4; ++rr) {
          const int row = rbase + i * 16 + rr;
          Cf[(size_t)row * DMODEL + col] = acc[i][j][rr] + bi;
        }
      }
    }
  }
}

// -------- flash attention w/ ALiBi + causal. grid (L/64, B*H), 256 thr -----
__launch_bounds__(256)
__global__ void k_attn(const short* __restrict__ q, const short* __restrict__ k,
                       const short* __restrict__ v, short* __restrict__ o) {
  constexpr int ST = 72;  // padded row stride
  __shared__ __align__(16) short Qs[64 * ST];
  __shared__ __align__(16) short Ks[64 * ST];
  __shared__ __align__(16) short Vt[64 * ST];
  __shared__ __align__(16) short Ps[4][16 * ST];
  const int tid = threadIdx.x;
  const int wave = tid >> 6, lane = tid & 63;
  const int quad = lane >> 4, l16 = lane & 15;
  const int qt = blockIdx.x, bh = blockIdx.y;
  const int h = bh & (NH - 1);
  const size_t base = (size_t)bh * SEQ * DH;
  const short* qb = q + base;
  const short* kbp = k + base;
  const short* vbp = v + base;
  const int q0 = qt * 64;
  const float LOG2E = 1.44269504088896f;
  const float slope2 = exp2f(-0.5f * (float)(h + 1)) * LOG2E;  // slope*log2e
  const float scale2 = 0.125f * LOG2E;                         // (1/sqrt(64))*log2e

#pragma unroll
  for (int p = 0; p < 2; ++p) {
    int c = p * 256 + tid;
    int row = c >> 3, col = (c & 7) * 8;
    *(short8*)&Qs[row * ST + col] = *(const short8*)&qb[(size_t)(q0 + row) * DH + col];
  }
  __syncthreads();
  short8 qa0 = *(const short8*)&Qs[(wave * 16 + l16) * ST + quad * 8];
  short8 qa1 = *(const short8*)&Qs[(wave * 16 + l16) * ST + 32 + quad * 8];

  f32x4 accO[4] = {};
  float m_i[4], l_i[4];
#pragma unroll
  for (int r = 0; r < 4; ++r) { m_i[r] = -INFINITY; l_i[r] = 0.f; }
  const int qrow_base = q0 + wave * 16 + quad * 4;

  for (int kt = 0; kt <= qt; ++kt) {
    const int kb = kt * 64;
    __syncthreads();  // previous tile fully consumed
#pragma unroll
    for (int p = 0; p < 2; ++p) {
      int c = p * 256 + tid;
      int row = c >> 3, col = (c & 7) * 8;
      *(short8*)&Ks[row * ST + col] = *(const short8*)&kbp[(size_t)(kb + row) * DH + col];
      short8 vv = *(const short8*)&vbp[(size_t)(kb + row) * DH + col];
#pragma unroll
      for (int j = 0; j < 8; ++j) Vt[(col + j) * ST + row] = vv[j];  // transpose V
    }
    __syncthreads();

    // S = Q K^T  (16 q-rows per wave x 64 keys)
    f32x4 s[4];
#pragma unroll
    for (int in = 0; in < 4; ++in) {
      short8 b0 = *(const short8*)&Ks[(in * 16 + l16) * ST + quad * 8];
      short8 b1 = *(const short8*)&Ks[(in * 16 + l16) * ST + 32 + quad * 8];
      f32x4 t = {};
      t = __builtin_amdgcn_mfma_f32_16x16x32_bf16(qa0, b0, t, 0, 0, 0);
      t = __builtin_amdgcn_mfma_f32_16x16x32_bf16(qa1, b1, t, 0, 0, 0);
      s[in] = t;
    }

    float alpha[4];
#pragma unroll
    for (int r = 0; r < 4; ++r) {
      const int qrow = qrow_base + r;
      float mx = -INFINITY;
#pragma unroll
      for (int in = 0; in < 4; ++in) {
        const int kcol = kb + in * 16 + l16;
        float val = s[in][r] * scale2 + slope2 * (float)(kcol - qrow);
        val = (kcol <= qrow) ? val : -INFINITY;
        s[in][r] = val;
        mx = fmaxf(mx, val);
      }
#pragma unroll
      for (int sh = 1; sh < 16; sh <<= 1) mx = fmaxf(mx, __shfl_xor(mx, sh, 64));
      const float newm = fmaxf(m_i[r], mx);
      alpha[r] = exp2f(m_i[r] - newm);
      m_i[r] = newm;
      float psum = 0.f;
#pragma unroll
      for (int in = 0; in < 4; ++in) {
        float pv = exp2f(s[in][r] - newm);
        s[in][r] = pv;
        psum += pv;
      }
#pragma unroll
      for (int sh = 1; sh < 16; sh <<= 1) psum += __shfl_xor(psum, sh, 64);
      l_i[r] = l_i[r] * alpha[r] + psum;
      // P: C-layout -> LDS (per-wave buffer), then re-read in A-layout
#pragma unroll
      for (int in = 0; in < 4; ++in)
        Ps[wave][(quad * 4 + r) * ST + in * 16 + l16] = f2bf(s[in][r]);
    }
#pragma unroll
    for (int in = 0; in < 4; ++in)
#pragma unroll
      for (int r = 0; r < 4; ++r) accO[in][r] *= alpha[r];

    short8 pa0 = *(const short8*)&Ps[wave][l16 * ST + quad * 8];
    short8 pa1 = *(const short8*)&Ps[wave][l16 * ST + 32 + quad * 8];
#pragma unroll
    for (int in = 0; in < 4; ++in) {
      short8 vb0 = *(const short8*)&Vt[(in * 16 + l16) * ST + quad * 8];
      short8 vb1 = *(const short8*)&Vt[(in * 16 + l16) * ST + 32 + quad * 8];
      accO[in] = __builtin_amdgcn_mfma_f32_16x16x32_bf16(pa0, vb0, accO[in], 0, 0, 0);
      accO[in] = __builtin_amdgcn_mfma_f32_16x16x32_bf16(pa1, vb1, accO[in], 0, 0, 0);
    }
  }

  // normalize + write [B, L, H, dh] (== [B, L, D]) as bf16
#pragma unroll
  for (int in = 0; in < 4; ++in)
#pragma unroll
    for (int r = 0; r < 4; ++r) {
      const int qrow = qrow_base + r;
      const int b = bh >> 4;
      float val = accO[in][r] / l_i[r];
      o[(((size_t)b * SEQ + qrow) * NH + h) * DH + in * 16 + l16] = f2bf(val);
    }
}

extern "C" void kernel_launch(void* const* d_in, const int* in_sizes, int n_in,
                              void* d_out, int out_size, void* d_ws, size_t ws_size,
                              hipStream_t stream) {
  const float* x = (const float*)d_in[0];      // [2,2048,1024]
  const float* w_in = (const float*)d_in[1];   // [1024,3072]
  const float* b_in = (const float*)d_in[2];   // [3072]
  const float* w_out = (const float*)d_in[3];  // [1024,1024]
  const float* b_out = (const float*)d_in[4];  // [1024]
  float* out = (float*)d_out;

  char* ws = (char*)d_ws;
  short* xb = (short*)(ws);                         // 8 MB  bf16 x
  short* w_in_t = (short*)(ws + (8u << 20));        // 6 MB  bf16 w_in^T [3072][1024]
  short* w_out_t = (short*)(ws + (14u << 20));      // 2 MB  bf16 w_out^T [1024][1024]
  short* qv = (short*)(ws + (16u << 20));           // 8 MB  [B,H,L,dh]
  short* kv = (short*)(ws + (24u << 20));           // 8 MB
  short* vv = (short*)(ws + (32u << 20));           // 8 MB
  short* ao = (short*)(ws + (40u << 20));           // 8 MB  attn out [B,L,D] bf16

  k_convert_x<<<4096, 256, 0, stream>>>(x, xb);
  k_transpose_bf16<<<dim3(96, 32), dim3(32, 8), 0, stream>>>(w_in, w_in_t, 1024, 3072);
  k_transpose_bf16<<<dim3(32, 32), dim3(32, 8), 0, stream>>>(w_out, w_out_t, 1024, 1024);
  k_gemm<0><<<dim3(24, 32), 256, 0, stream>>>(xb, w_in_t, b_in, nullptr, qv, kv, vv);
  k_attn<<<dim3(32, 32), 256, 0, stream>>>(qv, kv, vv, ao);
  k_gemm<1><<<dim3(8, 32), 256, 0, stream>>>(ao, w_out_t, b_out, out, nullptr, nullptr, nullptr);
}

// Round 2
// 216.131 us; speedup vs baseline: 1.5948x; 1.5948x over previous
//
#include <hip/hip_runtime.h>
#include <stdint.h>
#include <math.h>

#define NH 16
#define DH 64
#define SEQ 2048
#define NB 2
#define DMODEL 1024

typedef short short8 __attribute__((ext_vector_type(8)));
typedef short short4v __attribute__((ext_vector_type(4)));
typedef float f32x4 __attribute__((ext_vector_type(4)));

__device__ __forceinline__ short f2bf(float f) {
  union { float f; uint32_t u; } c; c.f = f;
  uint32_t u = c.u;
  uint32_t r = (u + 0x7FFFu + ((u >> 16) & 1u)) >> 16;
  return (short)(r & 0xFFFFu);
}

// ---------------- convert x (fp32 -> bf16), 4 elems/thread ----------------
__global__ void k_convert_x(const float* __restrict__ x, short* __restrict__ xb) {
  int i = blockIdx.x * blockDim.x + threadIdx.x;
  f32x4 v = ((const f32x4*)x)[i];
  short4v o;
  o[0] = f2bf(v[0]); o[1] = f2bf(v[1]); o[2] = f2bf(v[2]); o[3] = f2bf(v[3]);
  ((short4v*)xb)[i] = o;
}

// ------------- transpose+convert: in[R][C] fp32 -> out[C][R] bf16 ----------
__global__ void k_transpose_bf16(const float* __restrict__ in, short* __restrict__ out,
                                 int R, int C) {
  __shared__ float tile[32][33];
  int tx = threadIdx.x, ty = threadIdx.y;
  int c0 = blockIdx.x * 32, r0 = blockIdx.y * 32;
#pragma unroll
  for (int i = 0; i < 4; ++i)
    tile[ty + i * 8][tx] = in[(size_t)(r0 + ty + i * 8) * C + c0 + tx];
  __syncthreads();
#pragma unroll
  for (int i = 0; i < 4; ++i)
    out[(size_t)(c0 + ty + i * 8) * R + r0 + tx] = f2bf(tile[tx][ty + i * 8]);
}

// ---------------- GEMM: C[M,N] = A[M,K=1024] * Bt[N,K]^T + bias ------------
// MODE 0: scatter bf16 into q/k [B,H,L,dh], v transposed [B,H,dh,L]
// MODE 1: fp32 out [M,1024]
template <int MODE>
__launch_bounds__(256)
__global__ void k_gemm(const short* __restrict__ A, const short* __restrict__ Bt,
                       const float* __restrict__ bias, float* __restrict__ Cf,
                       short* __restrict__ qo, short* __restrict__ ko,
                       short* __restrict__ vo) {
  constexpr int KD = 1024;
  constexpr int ST = 40;  // padded LDS row stride (shorts): 2-way bank alias = free
  __shared__ __align__(16) short As[128 * ST];
  __shared__ __align__(16) short Bs[128 * ST];
  const int tid = threadIdx.x;
  const int wave = tid >> 6, lane = tid & 63;
  const int quad = lane >> 4, l16 = lane & 15;
  const int wm = wave >> 1, wn = wave & 1;
  const int tM = blockIdx.y * 128, tN = blockIdx.x * 128;

  f32x4 acc[4][4] = {};

  for (int k0 = 0; k0 < KD; k0 += 32) {
    __syncthreads();
#pragma unroll
    for (int p = 0; p < 2; ++p) {
      int c = p * 256 + tid;
      int row = c >> 2, col = (c & 3) * 8;
      *(short8*)&As[row * ST + col] =
          *(const short8*)&A[(size_t)(tM + row) * KD + k0 + col];
      *(short8*)&Bs[row * ST + col] =
          *(const short8*)&Bt[(size_t)(tN + row) * KD + k0 + col];
    }
    __syncthreads();
    short8 af[4], bfr[4];
#pragma unroll
    for (int i = 0; i < 4; ++i)
      af[i] = *(const short8*)&As[(wm * 64 + i * 16 + l16) * ST + quad * 8];
#pragma unroll
    for (int i = 0; i < 4; ++i)
      bfr[i] = *(const short8*)&Bs[(wn * 64 + i * 16 + l16) * ST + quad * 8];
#pragma unroll
    for (int i = 0; i < 4; ++i)
#pragma unroll
      for (int j = 0; j < 4; ++j)
        acc[i][j] = __builtin_amdgcn_mfma_f32_16x16x32_bf16(af[i], bfr[j], acc[i][j], 0, 0, 0);
  }

  const int rbase = tM + wm * 64 + quad * 4;
#pragma unroll
  for (int i = 0; i < 4; ++i) {
#pragma unroll
    for (int j = 0; j < 4; ++j) {
      const int col = tN + wn * 64 + j * 16 + l16;
      const float bi = bias[col];
      if (MODE == 0) {
        const int which = col >> 10;
        const int h = (col & 1023) >> 6, d = col & 63;
#pragma unroll
        for (int rr = 0; rr < 4; ++rr) {
          const int row = rbase + i * 16 + rr;
          const int b = row >> 11, li = row & 2047;
          if (which == 2) {
            // v transposed: [B,H,dh,L]
            vo[(((size_t)(b * NH + h)) * DH + d) * SEQ + li] = f2bf(acc[i][j][rr] + bi);
          } else {
            short* dst = (which == 0) ? qo : ko;
            dst[(((size_t)(b * NH + h)) * SEQ + li) * DH + d] = f2bf(acc[i][j][rr] + bi);
          }
        }
      } else {
#pragma unroll
        for (int rr = 0; rr < 4; ++rr) {
          const int row = rbase + i * 16 + rr;
          Cf[(size_t)row * DMODEL + col] = acc[i][j][rr] + bi;
        }
      }
    }
  }
}

// -------- flash attention w/ ALiBi + causal, fixed-max softmax -------------
// grid (16, B*H): block handles q-tile pair (31-pairid, pairid) -> 33 k-tiles each
__launch_bounds__(256)
__global__ void k_attn(const short* __restrict__ q, const short* __restrict__ k,
                       const short* __restrict__ vt, short* __restrict__ o) {
  constexpr int ST = 72;   // K/V/Q LDS row stride (shorts)
  constexpr int PST = 68;  // Ps row stride: quad bank offsets 0/8/16/24 -> conflict-free
  __shared__ __align__(16) short Qs[64 * ST];
  __shared__ __align__(16) short Ks[64 * ST];
  __shared__ __align__(16) short Vs[64 * ST];  // V^T tile: [d][k]
  __shared__ __align__(16) short Ps[4][16 * PST];
  const int tid = threadIdx.x;
  const int wave = tid >> 6, lane = tid & 63;
  const int quad = lane >> 4, l16 = lane & 15;
  const int pairid = blockIdx.x, bh = blockIdx.y;
  const int h = bh & (NH - 1);
  const size_t base = (size_t)bh * SEQ * DH;
  const float LOG2E = 1.44269504088896f;
  const float slope2 = exp2f(-0.5f * (float)(h + 1)) * LOG2E;  // slope*log2e
  const float scale2 = 0.125f * LOG2E;                         // (1/8)*log2e
  const float FM = 12.0f;  // fixed softmax max (scores bounded << 12; factor cancels)

  const int srow = tid >> 2, sseg = (tid & 3) * 16;  // staging coords: 64x64 tile

#pragma unroll
  for (int half = 0; half < 2; ++half) {
    const int qt = half ? pairid : (31 - pairid);
    const int q0 = qt * 64;
    __syncthreads();
    *(short8*)&Qs[srow * ST + sseg] = *(const short8*)&q[base + (size_t)(q0 + srow) * DH + sseg];
    *(short8*)&Qs[srow * ST + sseg + 8] = *(const short8*)&q[base + (size_t)(q0 + srow) * DH + sseg + 8];
    __syncthreads();
    const short8 qa0 = *(const short8*)&Qs[(wave * 16 + l16) * ST + quad * 8];
    const short8 qa1 = *(const short8*)&Qs[(wave * 16 + l16) * ST + 32 + quad * 8];

    f32x4 accO[4] = {};
    float lsum[4] = {0.f, 0.f, 0.f, 0.f};
    const int qrow_base = q0 + wave * 16 + quad * 4;
    float rp[4];
#pragma unroll
    for (int r = 0; r < 4; ++r) rp[r] = slope2 * (float)(qrow_base + r) + FM;

    for (int kt = 0; kt <= qt; ++kt) {
      const int kb = kt * 64;
      __syncthreads();
      *(short8*)&Ks[srow * ST + sseg] = *(const short8*)&k[base + (size_t)(kb + srow) * DH + sseg];
      *(short8*)&Ks[srow * ST + sseg + 8] = *(const short8*)&k[base + (size_t)(kb + srow) * DH + sseg + 8];
      *(short8*)&Vs[srow * ST + sseg] = *(const short8*)&vt[base + (size_t)srow * SEQ + kb + sseg];
      *(short8*)&Vs[srow * ST + sseg + 8] = *(const short8*)&vt[base + (size_t)srow * SEQ + kb + sseg + 8];
      __syncthreads();

      // S = Q K^T  (16 q-rows per wave x 64 keys)
      f32x4 s[4];
#pragma unroll
      for (int in = 0; in < 4; ++in) {
        short8 b0 = *(const short8*)&Ks[(in * 16 + l16) * ST + quad * 8];
        short8 b1 = *(const short8*)&Ks[(in * 16 + l16) * ST + 32 + quad * 8];
        f32x4 t = {};
        t = __builtin_amdgcn_mfma_f32_16x16x32_bf16(qa0, b0, t, 0, 0, 0);
        t = __builtin_amdgcn_mfma_f32_16x16x32_bf16(qa1, b1, t, 0, 0, 0);
        s[in] = t;
      }

      // p = exp2(s*scale2 + slope2*(kcol - qrow) - FM); no running max, no shuffles
      float cp[4];
#pragma unroll
      for (int in = 0; in < 4; ++in)
        cp[in] = slope2 * (float)(kb + in * 16 + l16);
      if (kt == qt) {  // diagonal: causal mask
#pragma unroll
        for (int in = 0; in < 4; ++in) {
          const int kcol = kb + in * 16 + l16;
#pragma unroll
          for (int r = 0; r < 4; ++r) {
            float p = exp2f(fmaf(s[in][r], scale2, cp[in] - rp[r]));
            p = (kcol <= qrow_base + r) ? p : 0.f;
            lsum[r] += p;
            Ps[wave][(quad * 4 + r) * PST + in * 16 + l16] = f2bf(p);
          }
        }
      } else {
#pragma unroll
        for (int in = 0; in < 4; ++in) {
#pragma unroll
          for (int r = 0; r < 4; ++r) {
            float p = exp2f(fmaf(s[in][r], scale2, cp[in] - rp[r]));
            lsum[r] += p;
            Ps[wave][(quad * 4 + r) * PST + in * 16 + l16] = f2bf(p);
          }
        }
      }

      // O += P V   (P re-read in A-layout from per-wave LDS; V^T already staged)
      const short8 pa0 = *(const short8*)&Ps[wave][l16 * PST + quad * 8];
      const short8 pa1 = *(const short8*)&Ps[wave][l16 * PST + 32 + quad * 8];
#pragma unroll
      for (int in = 0; in < 4; ++in) {
        short8 vb0 = *(const short8*)&Vs[(in * 16 + l16) * ST + quad * 8];
        short8 vb1 = *(const short8*)&Vs[(in * 16 + l16) * ST + 32 + quad * 8];
        accO[in] = __builtin_amdgcn_mfma_f32_16x16x32_bf16(pa0, vb0, accO[in], 0, 0, 0);
        accO[in] = __builtin_amdgcn_mfma_f32_16x16x32_bf16(pa1, vb1, accO[in], 0, 0, 0);
      }
    }

    // reduce l over the 16 lanes holding each row's k-columns (once per q-tile)
    float inv[4];
#pragma unroll
    for (int r = 0; r < 4; ++r) {
      float t = lsum[r];
#pragma unroll
      for (int sh = 1; sh < 16; sh <<= 1) t += __shfl_xor(t, sh, 64);
      inv[r] = 1.0f / t;
    }
    const int b = bh >> 4;
#pragma unroll
    for (int in = 0; in < 4; ++in)
#pragma unroll
      for (int r = 0; r < 4; ++r) {
        const int qrow = qrow_base + r;
        o[(((size_t)b * SEQ + qrow) * NH + h) * DH + in * 16 + l16] =
            f2bf(accO[in][r] * inv[r]);
      }
  }
}

extern "C" void kernel_launch(void* const* d_in, const int* in_sizes, int n_in,
                              void* d_out, int out_size, void* d_ws, size_t ws_size,
                              hipStream_t stream) {
  const float* x = (const float*)d_in[0];      // [2,2048,1024]
  const float* w_in = (const float*)d_in[1];   // [1024,3072]
  const float* b_in = (const float*)d_in[2];   // [3072]
  const float* w_out = (const float*)d_in[3];  // [1024,1024]
  const float* b_out = (const float*)d_in[4];  // [1024]
  float* out = (float*)d_out;

  char* ws = (char*)d_ws;
  short* xb = (short*)(ws);                         // 8 MB  bf16 x
  short* w_in_t = (short*)(ws + (8u << 20));        // 6 MB  bf16 w_in^T [3072][1024]
  short* w_out_t = (short*)(ws + (14u << 20));      // 2 MB  bf16 w_out^T [1024][1024]
  short* qv = (short*)(ws + (16u << 20));           // 8 MB  [B,H,L,dh]
  short* kv = (short*)(ws + (24u << 20));           // 8 MB  [B,H,L,dh]
  short* vv = (short*)(ws + (32u << 20));           // 8 MB  [B,H,dh,L]  (transposed)
  short* ao = (short*)(ws + (40u << 20));           // 8 MB  attn out [B,L,D] bf16

  k_convert_x<<<4096, 256, 0, stream>>>(x, xb);
  k_transpose_bf16<<<dim3(96, 32), dim3(32, 8), 0, stream>>>(w_in, w_in_t, 1024, 3072);
  k_transpose_bf16<<<dim3(32, 32), dim3(32, 8), 0, stream>>>(w_out, w_out_t, 1024, 1024);
  k_gemm<0><<<dim3(24, 32), 256, 0, stream>>>(xb, w_in_t, b_in, nullptr, qv, kv, vv);
  k_attn<<<dim3(16, 32), 256, 0, stream>>>(qv, kv, vv, ao);
  k_gemm<1><<<dim3(8, 32), 256, 0, stream>>>(ao, w_out_t, b_out, out, nullptr, nullptr, nullptr);
}

// Round 3
// 204.113 us; speedup vs baseline: 1.6887x; 1.0589x over previous
//
#include <hip/hip_runtime.h>
#include <stdint.h>
#include <math.h>

#define NH 16
#define DH 64
#define SEQ 2048
#define DMODEL 1024

typedef short short8 __attribute__((ext_vector_type(8)));
typedef short short4v __attribute__((ext_vector_type(4)));
typedef float f32x4 __attribute__((ext_vector_type(4)));
typedef __bf16 bf16x4 __attribute__((ext_vector_type(4)));

__device__ __forceinline__ short f2bf(float f) {
  __bf16 h = (__bf16)f;
  return __builtin_bit_cast(short, h);
}
__device__ __forceinline__ short4v cvt4(f32x4 v) {
  bf16x4 b = __builtin_convertvector(v, bf16x4);
  return __builtin_bit_cast(short4v, b);
}
__device__ __forceinline__ float fast_exp2(float x) {
#if __has_builtin(__builtin_amdgcn_exp2f)
  return __builtin_amdgcn_exp2f(x);
#else
  return exp2f(x);
#endif
}

typedef const __attribute__((address_space(1))) uint32_t* gp_t;
typedef __attribute__((address_space(3))) uint32_t* lp_t;
__device__ __forceinline__ void async16(const short* g, short* l) {
  __builtin_amdgcn_global_load_lds((gp_t)g, (lp_t)l, 16, 0, 0);
}

// ---------------- convert x (fp32 -> bf16), 4 elems/thread ----------------
__global__ void k_convert_x(const float* __restrict__ x, short* __restrict__ xb) {
  int i = blockIdx.x * blockDim.x + threadIdx.x;
  f32x4 v = ((const f32x4*)x)[i];
  short4v o;
  o[0] = f2bf(v[0]); o[1] = f2bf(v[1]); o[2] = f2bf(v[2]); o[3] = f2bf(v[3]);
  ((short4v*)xb)[i] = o;
}

// ------------- transpose+convert: in[R][C] fp32 -> out[C][R] bf16 ----------
__global__ void k_transpose_bf16(const float* __restrict__ in, short* __restrict__ out,
                                 int R, int C) {
  __shared__ float tile[32][33];
  int tx = threadIdx.x, ty = threadIdx.y;
  int c0 = blockIdx.x * 32, r0 = blockIdx.y * 32;
#pragma unroll
  for (int i = 0; i < 4; ++i)
    tile[ty + i * 8][tx] = in[(size_t)(r0 + ty + i * 8) * C + c0 + tx];
  __syncthreads();
#pragma unroll
  for (int i = 0; i < 4; ++i)
    out[(size_t)(c0 + ty + i * 8) * R + r0 + tx] = f2bf(tile[tx][ty + i * 8]);
}

// ---------------- GEMM: C[M,N] = A[M,K=1024] * Bt[N,K]^T + bias ------------
// m97 pattern: global_load_lds width=16, linear LDS ST=32 (no pad).
// MODE 0: scatter bf16 into q/k [B,H,L,dh], v transposed [B,H,dh,L]
// MODE 1: fp32 out [M,1024]
template <int MODE>
__launch_bounds__(256)
__global__ void k_gemm(const short* __restrict__ A, const short* __restrict__ Bt,
                       const float* __restrict__ bias, float* __restrict__ Cf,
                       short* __restrict__ qo, short* __restrict__ ko,
                       short* __restrict__ vo) {
  constexpr int KD = 1024;
  __shared__ __align__(16) short As[128 * 32];
  __shared__ __align__(16) short Bs[128 * 32];
  const int tid = threadIdx.x;
  const int wave = tid >> 6, lane = tid & 63;
  const int quad = lane >> 4, l16 = lane & 15;
  const int wm = wave >> 1, wn = wave & 1;
  const int tM = blockIdx.y * 128, tN = blockIdx.x * 128;

  // staging: chunk c = t*256+tid  (t=0,1): row=c>>2, col=(c&3)*8 shorts
  const int r0 = tid >> 2, cc = (tid & 3) * 8;
  const short* pA0 = A + (size_t)(tM + r0) * KD + cc;
  const short* pA1 = pA0 + (size_t)64 * KD;
  const short* pB0 = Bt + (size_t)(tN + r0) * KD + cc;
  const short* pB1 = pB0 + (size_t)64 * KD;
  short* lA0 = &As[tid * 8];
  short* lA1 = &As[(256 + tid) * 8];
  short* lB0 = &Bs[tid * 8];
  short* lB1 = &Bs[(256 + tid) * 8];

  f32x4 acc[4][4] = {};

  for (int k0 = 0; k0 < KD; k0 += 32) {
    __syncthreads();
    async16(pA0 + k0, lA0);
    async16(pA1 + k0, lA1);
    async16(pB0 + k0, lB0);
    async16(pB1 + k0, lB1);
    __syncthreads();
    short8 af[4], bfr[4];
#pragma unroll
    for (int i = 0; i < 4; ++i)
      af[i] = *(const short8*)&As[(wm * 64 + i * 16 + l16) * 32 + quad * 8];
#pragma unroll
    for (int i = 0; i < 4; ++i)
      bfr[i] = *(const short8*)&Bs[(wn * 64 + i * 16 + l16) * 32 + quad * 8];
#pragma unroll
    for (int i = 0; i < 4; ++i)
#pragma unroll
      for (int j = 0; j < 4; ++j)
        acc[i][j] = __builtin_amdgcn_mfma_f32_16x16x32_bf16(af[i], bfr[j], acc[i][j], 0, 0, 0);
  }

  const int rbase = tM + wm * 64 + quad * 4;
#pragma unroll
  for (int i = 0; i < 4; ++i) {
#pragma unroll
    for (int j = 0; j < 4; ++j) {
      const int col = tN + wn * 64 + j * 16 + l16;
      const float bi = bias[col];
      if (MODE == 0) {
        const int which = col >> 10;  // uniform per block (tN multiple of 128)
        const int h = (col & 1023) >> 6, d = col & 63;
        if (which == 2) {
          // v transposed [B,H,dh,L]: li consecutive over rr -> packed b64 store
          const int row0 = rbase + i * 16;
          const int b = row0 >> 11, li0 = row0 & 2047;
          f32x4 t;
#pragma unroll
          for (int rr = 0; rr < 4; ++rr) t[rr] = acc[i][j][rr] + bi;
          *(short4v*)&vo[(((size_t)(b * NH + h)) * DH + d) * SEQ + li0] = cvt4(t);
        } else {
          short* dst = (which == 0) ? qo : ko;
#pragma unroll
          for (int rr = 0; rr < 4; ++rr) {
            const int row = rbase + i * 16 + rr;
            const int b = row >> 11, li = row & 2047;
            dst[(((size_t)(b * NH + h)) * SEQ + li) * DH + d] = f2bf(acc[i][j][rr] + bi);
          }
        }
      } else {
#pragma unroll
        for (int rr = 0; rr < 4; ++rr) {
          const int row = rbase + i * 16 + rr;
          Cf[(size_t)row * DMODEL + col] = acc[i][j][rr] + bi;
        }
      }
    }
  }
}

// -------- flash attention, S^T orientation, fixed-max softmax --------------
// grid (16, B*H): block handles q-tile pair (31-pairid, pairid) -> 33 k-tiles.
// All LDS tiles 64x64 shorts, XOR-swizzled chunks (ch^(row&7)) so
// global_load_lds staging + conflict-floor b128 frag reads coexist.
__launch_bounds__(256)
__global__ void k_attn(const short* __restrict__ q, const short* __restrict__ k,
                       const short* __restrict__ vt, short* __restrict__ o) {
  __shared__ __align__(16) short Qs[64 * 64];
  __shared__ __align__(16) short Ks[64 * 64];
  __shared__ __align__(16) short Vs[64 * 64];   // V^T tile [d][key]
  __shared__ __align__(16) short Ps[4][16 * 64];  // per-wave P [q][key]
  const int tid = threadIdx.x;
  const int wave = tid >> 6, lane = tid & 63;
  const int quad = lane >> 4, l16 = lane & 15;
  const int sw = l16 & 7;
  const int pairid = blockIdx.x, bh = blockIdx.y;
  const int h = bh & (NH - 1);
  const size_t base = (size_t)bh * SEQ * DH;
  const float LOG2E = 1.44269504088896f;
  const float slope2 = exp2f(-0.5f * (float)(h + 1)) * LOG2E;  // slope*log2e
  const float scale2 = 0.125f * LOG2E;                         // (1/8)*log2e
  const float FM = 12.0f;  // fixed softmax max; cancels in O/l exactly

  // staging chunks: c = t*256+tid, row=c>>3, ch=(c&7)^(row&7); lds off = c*16B
  const int c0i = tid, c1i = 256 + tid;
  const int r0 = c0i >> 3, ch0 = (c0i & 7) ^ (r0 & 7);
  const int r1 = c1i >> 3, ch1 = (c1i & 7) ^ (r1 & 7);
  const int qk_off0 = r0 * DH + ch0 * 8;
  const int qk_off1 = r1 * DH + ch1 * 8;
  const int v_off0 = r0 * SEQ + ch0 * 8;
  const int v_off1 = r1 * SEQ + ch1 * 8;
  short* lQ0 = &Qs[c0i * 8]; short* lQ1 = &Qs[c1i * 8];
  short* lK0 = &Ks[c0i * 8]; short* lK1 = &Ks[c1i * 8];
  short* lV0 = &Vs[c0i * 8]; short* lV1 = &Vs[c1i * 8];

  // frag read column offsets (swizzled): chunk quad^sw, and ^4 for +32
  const int col0 = ((quad ^ sw) << 3);
  const int col1 = col0 ^ 32;
  // Ps write offsets: row=l16, key col 16*in+4*quad -> chunk 2*in+(quad>>1),
  // half (quad&1); swizzled by ^sw.
  int psoff[4];
#pragma unroll
  for (int in = 0; in < 4; ++in)
    psoff[in] = l16 * 64 + (((2 * in + (quad >> 1)) ^ sw) << 3) + (quad & 1) * 4;
  const int qlim4 = wave * 16 + l16 - 4 * quad;  // diag mask: keep 16*in+r <= qlim4
  const float s64 = slope2 * 64.0f;
  float rc[4];
#pragma unroll
  for (int r = 0; r < 4; ++r) rc[r] = slope2 * (float)r;

#pragma unroll
  for (int half = 0; half < 2; ++half) {
    const int qt = half ? pairid : (31 - pairid);
    const int q0 = qt * 64;
    __syncthreads();
    {
      const short* qb = q + base + (size_t)q0 * DH;
      async16(qb + qk_off0, lQ0);
      async16(qb + qk_off1, lQ1);
    }
    __syncthreads();
    const short8 qb0 = *(const short8*)&Qs[(wave * 16 + l16) * 64 + col0];
    const short8 qb1 = *(const short8*)&Qs[(wave * 16 + l16) * 64 + col1];

    f32x4 accO[4] = {};
    float lsum = 0.f;
    const int qrow = q0 + wave * 16 + l16;  // each lane owns ONE q-row
    const float qoff = -slope2 * (float)qrow - FM + slope2 * (float)(4 * quad);
    float inoff[4];
#pragma unroll
    for (int in = 0; in < 4; ++in)
      inoff[in] = qoff + slope2 * (float)(16 * in);  // tracks slope2*(kb+16in)+qoff

    const short* kp = k + base;
    const short* vp = vt + base;
    for (int kt = 0; kt <= qt; ++kt) {
      __syncthreads();
      async16(kp + qk_off0, lK0);
      async16(kp + qk_off1, lK1);
      async16(vp + v_off0, lV0);
      async16(vp + v_off1, lV1);
      kp += 64 * DH;
      vp += 64;
      __syncthreads();

      // S^T = K Q^T : lane holds keys 16*in+4*quad+r for q-row l16
      f32x4 s[4];
#pragma unroll
      for (int in = 0; in < 4; ++in) {
        const short8 ka0 = *(const short8*)&Ks[(in * 16 + l16) * 64 + col0];
        const short8 ka1 = *(const short8*)&Ks[(in * 16 + l16) * 64 + col1];
        f32x4 t = {};
        t = __builtin_amdgcn_mfma_f32_16x16x32_bf16(ka0, qb0, t, 0, 0, 0);
        t = __builtin_amdgcn_mfma_f32_16x16x32_bf16(ka1, qb1, t, 0, 0, 0);
        s[in] = t;
      }

      if (kt == qt) {  // diagonal: causal mask
#pragma unroll
        for (int in = 0; in < 4; ++in) {
          f32x4 p;
#pragma unroll
          for (int r = 0; r < 4; ++r) {
            float val = fast_exp2(fmaf(s[in][r], scale2, inoff[in] + rc[r]));
            val = (16 * in + r <= qlim4) ? val : 0.f;
            p[r] = val;
            lsum += val;
          }
          *(short4v*)&Ps[wave][psoff[in]] = cvt4(p);
        }
      } else {
#pragma unroll
        for (int in = 0; in < 4; ++in) {
          f32x4 p;
#pragma unroll
          for (int r = 0; r < 4; ++r) {
            float val = fast_exp2(fmaf(s[in][r], scale2, inoff[in] + rc[r]));
            p[r] = val;
            lsum += val;
          }
          *(short4v*)&Ps[wave][psoff[in]] = cvt4(p);
        }
      }
#pragma unroll
      for (int in = 0; in < 4; ++in) inoff[in] += s64;

      // O^T += V^T P^T : A=V^T rows (m=d), B=P rows (n=q)
      const short8 pa0 = *(const short8*)&Ps[wave][l16 * 64 + col0];
      const short8 pa1 = *(const short8*)&Ps[wave][l16 * 64 + col1];
#pragma unroll
      for (int i = 0; i < 4; ++i) {
        const short8 va0 = *(const short8*)&Vs[(i * 16 + l16) * 64 + col0];
        const short8 va1 = *(const short8*)&Vs[(i * 16 + l16) * 64 + col1];
        accO[i] = __builtin_amdgcn_mfma_f32_16x16x32_bf16(va0, pa0, accO[i], 0, 0, 0);
        accO[i] = __builtin_amdgcn_mfma_f32_16x16x32_bf16(va1, pa1, accO[i], 0, 0, 0);
      }
    }

    // full row-sum: reduce across quads (lanes same l16), once per q-tile
    lsum += __shfl_xor(lsum, 16, 64);
    lsum += __shfl_xor(lsum, 32, 64);
    const float inv = 1.0f / lsum;

    const int b = bh >> 4;
    short* ob = o + ((((size_t)b * SEQ + qrow) * NH + h) * DH + 4 * quad);
#pragma unroll
    for (int i = 0; i < 4; ++i) {
      f32x4 t;
#pragma unroll
      for (int r = 0; r < 4; ++r) t[r] = accO[i][r] * inv;
      *(short4v*)&ob[16 * i] = cvt4(t);  // d = 16i+4quad+r contiguous
    }
  }
}

extern "C" void kernel_launch(void* const* d_in, const int* in_sizes, int n_in,
                              void* d_out, int out_size, void* d_ws, size_t ws_size,
                              hipStream_t stream) {
  const float* x = (const float*)d_in[0];      // [2,2048,1024]
  const float* w_in = (const float*)d_in[1];   // [1024,3072]
  const float* b_in = (const float*)d_in[2];   // [3072]
  const float* w_out = (const float*)d_in[3];  // [1024,1024]
  const float* b_out = (const float*)d_in[4];  // [1024]
  float* out = (float*)d_out;

  char* ws = (char*)d_ws;
  short* xb = (short*)(ws);                     // 8 MB  bf16 x
  short* w_in_t = (short*)(ws + (8u << 20));    // 6 MB  bf16 w_in^T [3072][1024]
  short* w_out_t = (short*)(ws + (14u << 20));  // 2 MB  bf16 w_out^T [1024][1024]
  short* qv = (short*)(ws + (16u << 20));       // 8 MB  [B,H,L,dh]
  short* kv = (short*)(ws + (24u << 20));       // 8 MB  [B,H,L,dh]
  short* vv = (short*)(ws + (32u << 20));       // 8 MB  [B,H,dh,L] (transposed)
  short* ao = (short*)(ws + (40u << 20));       // 8 MB  attn out [B,L,D] bf16

  k_convert_x<<<4096, 256, 0, stream>>>(x, xb);
  k_transpose_bf16<<<dim3(96, 32), dim3(32, 8), 0, stream>>>(w_in, w_in_t, 1024, 3072);
  k_transpose_bf16<<<dim3(32, 32), dim3(32, 8), 0, stream>>>(w_out, w_out_t, 1024, 1024);
  k_gemm<0><<<dim3(24, 32), 256, 0, stream>>>(xb, w_in_t, b_in, nullptr, qv, kv, vv);
  k_attn<<<dim3(16, 32), 256, 0, stream>>>(qv, kv, vv, ao);
  k_gemm<1><<<dim3(8, 32), 256, 0, stream>>>(ao, w_out_t, b_out, out, nullptr, nullptr, nullptr);
}

// Round 4
// 192.511 us; speedup vs baseline: 1.7905x; 1.0603x over previous
//
#include <hip/hip_runtime.h>
#include <stdint.h>
#include <math.h>

#define NH 16
#define DH 64
#define SEQ 2048
#define DMODEL 1024

typedef short short8 __attribute__((ext_vector_type(8)));
typedef short short4v __attribute__((ext_vector_type(4)));
typedef float f32x4 __attribute__((ext_vector_type(4)));
typedef __bf16 bf16x4 __attribute__((ext_vector_type(4)));

__device__ __forceinline__ short f2bf(float f) {
  __bf16 h = (__bf16)f;
  return __builtin_bit_cast(short, h);
}
__device__ __forceinline__ short4v cvt4(f32x4 v) {
  bf16x4 b = __builtin_convertvector(v, bf16x4);
  return __builtin_bit_cast(short4v, b);
}
__device__ __forceinline__ float fast_exp2(float x) {
#if __has_builtin(__builtin_amdgcn_exp2f)
  return __builtin_amdgcn_exp2f(x);
#else
  return exp2f(x);
#endif
}

typedef const __attribute__((address_space(1))) uint32_t* gp_t;
typedef __attribute__((address_space(3))) uint32_t* lp_t;
__device__ __forceinline__ void async16(const short* g, short* l) {
  __builtin_amdgcn_global_load_lds((gp_t)g, (lp_t)l, 16, 0, 0);
}

// ---------------- convert x (fp32 -> bf16), 4 elems/thread ----------------
__global__ void k_convert_x(const float* __restrict__ x, short* __restrict__ xb) {
  int i = blockIdx.x * blockDim.x + threadIdx.x;
  f32x4 v = ((const f32x4*)x)[i];
  short4v o;
  o[0] = f2bf(v[0]); o[1] = f2bf(v[1]); o[2] = f2bf(v[2]); o[3] = f2bf(v[3]);
  ((short4v*)xb)[i] = o;
}

// ------------- transpose+convert: in[R][C] fp32 -> out[C][R] bf16 ----------
__global__ void k_transpose_bf16(const float* __restrict__ in, short* __restrict__ out,
                                 int R, int C) {
  __shared__ float tile[32][33];
  int tx = threadIdx.x, ty = threadIdx.y;
  int c0 = blockIdx.x * 32, r0 = blockIdx.y * 32;
#pragma unroll
  for (int i = 0; i < 4; ++i)
    tile[ty + i * 8][tx] = in[(size_t)(r0 + ty + i * 8) * C + c0 + tx];
  __syncthreads();
#pragma unroll
  for (int i = 0; i < 4; ++i)
    out[(size_t)(c0 + ty + i * 8) * R + r0 + tx] = f2bf(tile[tx][ty + i * 8]);
}

// ---------------- GEMM: C[M,N] = A[M,K=1024] * Bt[N,K]^T + bias ------------
// BK=64: 16 K-iters x 32 MFMA (halves barrier drains vs BK=32).
// LDS tiles 128x64, XOR-chunk-swizzled so global_load_lds (linear, wave-
// uniform-base) coexists with conflict-free b128 frag reads.
// MODE 0: scatter bf16 into q/k [B,H,L,dh], v transposed [B,H,dh,L]
// MODE 1: fp32 out [M,1024]
template <int MODE>
__launch_bounds__(256, 3)
__global__ void k_gemm(const short* __restrict__ A, const short* __restrict__ Bt,
                       const float* __restrict__ bias, float* __restrict__ Cf,
                       short* __restrict__ qo, short* __restrict__ ko,
                       short* __restrict__ vo) {
  constexpr int KD = 1024;
  __shared__ __align__(16) short As[128 * 64];  // 16 KB
  __shared__ __align__(16) short Bs[128 * 64];  // 16 KB
  const int tid = threadIdx.x;
  const int wave = tid >> 6, lane = tid & 63;
  const int quad = lane >> 4, l16 = lane & 15;
  const int wm = wave >> 1, wn = wave & 1;
  const int tM = blockIdx.y * 128, tN = blockIdx.x * 128;

  // staging: 4 chunks (16B) per thread per matrix. c = t*256+tid,
  // row=c>>3, global chunk = (c&7)^(row&7), LDS position = c (linear).
  const short* pA[4];
  const short* pB[4];
  short* lA[4];
  short* lB[4];
#pragma unroll
  for (int t = 0; t < 4; ++t) {
    const int c = t * 256 + tid;
    const int row = c >> 3, gch = (c & 7) ^ (row & 7);
    pA[t] = A + (size_t)(tM + row) * KD + gch * 8;
    pB[t] = Bt + (size_t)(tN + row) * KD + gch * 8;
    lA[t] = &As[c * 8];
    lB[t] = &Bs[c * 8];
  }

  // frag read columns: chunk j wanted -> LDS offset ((j^(l16&7))*8 shorts
  const int sw = l16 & 7;
  const int col0 = (quad ^ sw) << 3;  // chunks 0..3 (k 0..31)
  const int col1 = col0 ^ 32;         // chunks 4..7 (k 32..63)

  f32x4 acc[4][4] = {};

  for (int k0 = 0; k0 < KD; k0 += 64) {
    __syncthreads();
#pragma unroll
    for (int t = 0; t < 4; ++t) {
      async16(pA[t] + k0, lA[t]);
      async16(pB[t] + k0, lB[t]);
    }
    __syncthreads();
#pragma unroll
    for (int kh = 0; kh < 2; ++kh) {
      const int col = kh ? col1 : col0;
      short8 af[4], bfr[4];
#pragma unroll
      for (int i = 0; i < 4; ++i)
        af[i] = *(const short8*)&As[(wm * 64 + i * 16 + l16) * 64 + col];
#pragma unroll
      for (int i = 0; i < 4; ++i)
        bfr[i] = *(const short8*)&Bs[(wn * 64 + i * 16 + l16) * 64 + col];
#pragma unroll
      for (int i = 0; i < 4; ++i)
#pragma unroll
        for (int j = 0; j < 4; ++j)
          acc[i][j] = __builtin_amdgcn_mfma_f32_16x16x32_bf16(af[i], bfr[j], acc[i][j], 0, 0, 0);
    }
  }

  const int rbase = tM + wm * 64 + quad * 4;
#pragma unroll
  for (int i = 0; i < 4; ++i) {
#pragma unroll
    for (int j = 0; j < 4; ++j) {
      const int col = tN + wn * 64 + j * 16 + l16;
      const float bi = bias[col];
      if (MODE == 0) {
        const int which = col >> 10;  // uniform per block (tN multiple of 128)
        const int h = (col & 1023) >> 6, d = col & 63;
        if (which == 2) {
          // v transposed [B,H,dh,L]: li consecutive over rr -> packed b64 store
          const int row0 = rbase + i * 16;
          const int b = row0 >> 11, li0 = row0 & 2047;
          f32x4 t;
#pragma unroll
          for (int rr = 0; rr < 4; ++rr) t[rr] = acc[i][j][rr] + bi;
          *(short4v*)&vo[(((size_t)(b * NH + h)) * DH + d) * SEQ + li0] = cvt4(t);
        } else {
          short* dst = (which == 0) ? qo : ko;
#pragma unroll
          for (int rr = 0; rr < 4; ++rr) {
            const int row = rbase + i * 16 + rr;
            const int b = row >> 11, li = row & 2047;
            dst[(((size_t)(b * NH + h)) * SEQ + li) * DH + d] = f2bf(acc[i][j][rr] + bi);
          }
        }
      } else {
#pragma unroll
        for (int rr = 0; rr < 4; ++rr) {
          const int row = rbase + i * 16 + rr;
          Cf[(size_t)row * DMODEL + col] = acc[i][j][rr] + bi;
        }
      }
    }
  }
}

// -------- flash attention, S^T orientation, fixed-max softmax --------------
// grid (32, B*H): one q-tile per block, qt = 31-blockIdx.x (big tiles first;
// 1024 blocks -> 4 resident/CU, dynamic refill absorbs triangular imbalance).
__launch_bounds__(256)
__global__ void k_attn(const short* __restrict__ q, const short* __restrict__ k,
                       const short* __restrict__ vt, short* __restrict__ o) {
  __shared__ __align__(16) short Qs[64 * 64];
  __shared__ __align__(16) short Ks[64 * 64];
  __shared__ __align__(16) short Vs[64 * 64];     // V^T tile [d][key]
  __shared__ __align__(16) short Ps[4][16 * 64];  // per-wave P [q][key]
  const int tid = threadIdx.x;
  const int wave = tid >> 6, lane = tid & 63;
  const int quad = lane >> 4, l16 = lane & 15;
  const int sw = l16 & 7;
  const int qt = 31 - blockIdx.x, bh = blockIdx.y;
  const int h = bh & (NH - 1);
  const size_t base = (size_t)bh * SEQ * DH;
  const float LOG2E = 1.44269504088896f;
  const float slope2 = exp2f(-0.5f * (float)(h + 1)) * LOG2E;  // slope*log2e
  const float scale2 = 0.125f * LOG2E;                         // (1/8)*log2e
  const float FM = 12.0f;  // fixed softmax max; cancels in O/l exactly

  // staging chunks: c = t*256+tid, row=c>>3, ch=(c&7)^(row&7); lds off = c*16B
  const int c0i = tid, c1i = 256 + tid;
  const int r0 = c0i >> 3, ch0 = (c0i & 7) ^ (r0 & 7);
  const int r1 = c1i >> 3, ch1 = (c1i & 7) ^ (r1 & 7);
  const int qk_off0 = r0 * DH + ch0 * 8;
  const int qk_off1 = r1 * DH + ch1 * 8;
  const int v_off0 = r0 * SEQ + ch0 * 8;
  const int v_off1 = r1 * SEQ + ch1 * 8;
  short* lQ0 = &Qs[c0i * 8]; short* lQ1 = &Qs[c1i * 8];
  short* lK0 = &Ks[c0i * 8]; short* lK1 = &Ks[c1i * 8];
  short* lV0 = &Vs[c0i * 8]; short* lV1 = &Vs[c1i * 8];

  // frag read column offsets (swizzled)
  const int col0 = ((quad ^ sw) << 3);
  const int col1 = col0 ^ 32;
  // Ps write offsets: row=l16, key col 16*in+4*quad -> chunk 2*in+(quad>>1),
  // half (quad&1); swizzled by ^sw.
  int psoff[4];
#pragma unroll
  for (int in = 0; in < 4; ++in)
    psoff[in] = l16 * 64 + (((2 * in + (quad >> 1)) ^ sw) << 3) + (quad & 1) * 4;
  const int qlim4 = wave * 16 + l16 - 4 * quad;  // diag mask: keep 16*in+r <= qlim4
  const float s64 = slope2 * 64.0f;
  float rc[4];
#pragma unroll
  for (int r = 0; r < 4; ++r) rc[r] = slope2 * (float)r;

  const int q0 = qt * 64;
  {
    const short* qb = q + base + (size_t)q0 * DH;
    async16(qb + qk_off0, lQ0);
    async16(qb + qk_off1, lQ1);
  }
  __syncthreads();
  const short8 qb0 = *(const short8*)&Qs[(wave * 16 + l16) * 64 + col0];
  const short8 qb1 = *(const short8*)&Qs[(wave * 16 + l16) * 64 + col1];

  f32x4 accO[4] = {};
  float lsum = 0.f;
  const int qrow = q0 + wave * 16 + l16;  // each lane owns ONE q-row
  const float qoff = -slope2 * (float)qrow - FM + slope2 * (float)(4 * quad);
  float inoff[4];
#pragma unroll
  for (int in = 0; in < 4; ++in)
    inoff[in] = qoff + slope2 * (float)(16 * in);  // tracks slope2*(kb+16in)+qoff

  const short* kp = k + base;
  const short* vp = vt + base;
  for (int kt = 0; kt <= qt; ++kt) {
    __syncthreads();
    async16(kp + qk_off0, lK0);
    async16(kp + qk_off1, lK1);
    async16(vp + v_off0, lV0);
    async16(vp + v_off1, lV1);
    kp += 64 * DH;
    vp += 64;
    __syncthreads();

    // S^T = K Q^T : lane holds keys 16*in+4*quad+r for q-row l16
    f32x4 s[4];
#pragma unroll
    for (int in = 0; in < 4; ++in) {
      const short8 ka0 = *(const short8*)&Ks[(in * 16 + l16) * 64 + col0];
      const short8 ka1 = *(const short8*)&Ks[(in * 16 + l16) * 64 + col1];
      f32x4 t = {};
      t = __builtin_amdgcn_mfma_f32_16x16x32_bf16(ka0, qb0, t, 0, 0, 0);
      t = __builtin_amdgcn_mfma_f32_16x16x32_bf16(ka1, qb1, t, 0, 0, 0);
      s[in] = t;
    }

    if (kt == qt) {  // diagonal: causal mask
#pragma unroll
      for (int in = 0; in < 4; ++in) {
        f32x4 p;
#pragma unroll
        for (int r = 0; r < 4; ++r) {
          float val = fast_exp2(fmaf(s[in][r], scale2, inoff[in] + rc[r]));
          val = (16 * in + r <= qlim4) ? val : 0.f;
          p[r] = val;
          lsum += val;
        }
        *(short4v*)&Ps[wave][psoff[in]] = cvt4(p);
      }
    } else {
#pragma unroll
      for (int in = 0; in < 4; ++in) {
        f32x4 p;
#pragma unroll
        for (int r = 0; r < 4; ++r) {
          float val = fast_exp2(fmaf(s[in][r], scale2, inoff[in] + rc[r]));
          p[r] = val;
          lsum += val;
        }
        *(short4v*)&Ps[wave][psoff[in]] = cvt4(p);
      }
    }
#pragma unroll
    for (int in = 0; in < 4; ++in) inoff[in] += s64;

    // O^T += V^T P^T : A=V^T rows (m=d), B=P rows (n=q)
    const short8 pa0 = *(const short8*)&Ps[wave][l16 * 64 + col0];
    const short8 pa1 = *(const short8*)&Ps[wave][l16 * 64 + col1];
#pragma unroll
    for (int i = 0; i < 4; ++i) {
      const short8 va0 = *(const short8*)&Vs[(i * 16 + l16) * 64 + col0];
      const short8 va1 = *(const short8*)&Vs[(i * 16 + l16) * 64 + col1];
      accO[i] = __builtin_amdgcn_mfma_f32_16x16x32_bf16(va0, pa0, accO[i], 0, 0, 0);
      accO[i] = __builtin_amdgcn_mfma_f32_16x16x32_bf16(va1, pa1, accO[i], 0, 0, 0);
    }
  }

  // full row-sum: reduce across quads (lanes same l16), once per q-tile
  lsum += __shfl_xor(lsum, 16, 64);
  lsum += __shfl_xor(lsum, 32, 64);
  const float inv = 1.0f / lsum;

  const int b = bh >> 4;
  short* ob = o + ((((size_t)b * SEQ + qrow) * NH + h) * DH + 4 * quad);
#pragma unroll
  for (int i = 0; i < 4; ++i) {
    f32x4 t;
#pragma unroll
    for (int r = 0; r < 4; ++r) t[r] = accO[i][r] * inv;
    *(short4v*)&ob[16 * i] = cvt4(t);  // d = 16i+4quad+r contiguous
  }
}

extern "C" void kernel_launch(void* const* d_in, const int* in_sizes, int n_in,
                              void* d_out, int out_size, void* d_ws, size_t ws_size,
                              hipStream_t stream) {
  const float* x = (const float*)d_in[0];      // [2,2048,1024]
  const float* w_in = (const float*)d_in[1];   // [1024,3072]
  const float* b_in = (const float*)d_in[2];   // [3072]
  const float* w_out = (const float*)d_in[3];  // [1024,1024]
  const float* b_out = (const float*)d_in[4];  // [1024]
  float* out = (float*)d_out;

  char* ws = (char*)d_ws;
  short* xb = (short*)(ws);                     // 8 MB  bf16 x
  short* w_in_t = (short*)(ws + (8u << 20));    // 6 MB  bf16 w_in^T [3072][1024]
  short* w_out_t = (short*)(ws + (14u << 20));  // 2 MB  bf16 w_out^T [1024][1024]
  short* qv = (short*)(ws + (16u << 20));       // 8 MB  [B,H,L,dh]
  short* kv = (short*)(ws + (24u << 20));       // 8 MB  [B,H,L,dh]
  short* vv = (short*)(ws + (32u << 20));       // 8 MB  [B,H,dh,L] (transposed)
  short* ao = (short*)(ws + (40u << 20));       // 8 MB  attn out [B,L,D] bf16

  k_convert_x<<<4096, 256, 0, stream>>>(x, xb);
  k_transpose_bf16<<<dim3(96, 32), dim3(32, 8), 0, stream>>>(w_in, w_in_t, 1024, 3072);
  k_transpose_bf16<<<dim3(32, 32), dim3(32, 8), 0, stream>>>(w_out, w_out_t, 1024, 1024);
  k_gemm<0><<<dim3(24, 32), 256, 0, stream>>>(xb, w_in_t, b_in, nullptr, qv, kv, vv);
  k_attn<<<dim3(32, 32), 256, 0, stream>>>(qv, kv, vv, ao);
  k_gemm<1><<<dim3(8, 32), 256, 0, stream>>>(ao, w_out_t, b_out, out, nullptr, nullptr, nullptr);
}

// Round 5
// 173.830 us; speedup vs baseline: 1.9829x; 1.1075x over previous
//
#include <hip/hip_runtime.h>
#include <stdint.h>
#include <math.h>

#define NH 16
#define DH 64
#define SEQ 2048
#define DMODEL 1024

typedef short short8 __attribute__((ext_vector_type(8)));
typedef short short4v __attribute__((ext_vector_type(4)));
typedef float f32x4 __attribute__((ext_vector_type(4)));
typedef __bf16 bf16x4 __attribute__((ext_vector_type(4)));

__device__ __forceinline__ short f2bf(float f) {
  __bf16 h = (__bf16)f;
  return __builtin_bit_cast(short, h);
}
__device__ __forceinline__ short4v cvt4(f32x4 v) {
  bf16x4 b = __builtin_convertvector(v, bf16x4);
  return __builtin_bit_cast(short4v, b);
}
__device__ __forceinline__ float fast_exp2(float x) {
#if __has_builtin(__builtin_amdgcn_exp2f)
  return __builtin_amdgcn_exp2f(x);
#else
  return exp2f(x);
#endif
}

typedef const __attribute__((address_space(1))) uint32_t* gp_t;
typedef __attribute__((address_space(3))) uint32_t* lp_t;
__device__ __forceinline__ void async16(const short* g, short* l) {
  __builtin_amdgcn_global_load_lds((gp_t)g, (lp_t)l, 16, 0, 0);
}

// ---- fused prep: x fp32->bf16 | w_in^T bf16 | w_out^T bf16 (one launch) ----
__device__ __forceinline__ void transpose_tile(const float* __restrict__ in,
                                               short* __restrict__ out, int R, int C,
                                               int t, int tilesX, int tid) {
  __shared__ float tile[32][33];
  const int tx = tid & 31, ty = tid >> 5;  // 32 x 8
  const int c0 = (t % tilesX) * 32, r0 = (t / tilesX) * 32;
#pragma unroll
  for (int i = 0; i < 4; ++i)
    tile[ty + i * 8][tx] = in[(size_t)(r0 + ty + i * 8) * C + c0 + tx];
  __syncthreads();
#pragma unroll
  for (int i = 0; i < 4; ++i)
    out[(size_t)(c0 + ty + i * 8) * R + r0 + tx] = f2bf(tile[tx][ty + i * 8]);
}

__global__ void k_prep(const float* __restrict__ x, short* __restrict__ xb,
                       const float* __restrict__ w_in, short* __restrict__ w_in_t,
                       const float* __restrict__ w_out, short* __restrict__ w_out_t) {
  const int tid = threadIdx.x;
  const int blk = blockIdx.x;
  if (blk < 4096) {  // x convert: 4096*256*4 = 4.19M elems
    const int i = blk * 256 + tid;
    f32x4 v = ((const f32x4*)x)[i];
    ((short4v*)xb)[i] = cvt4(v);
  } else if (blk < 4096 + 3072) {  // w_in [1024,3072] -> [3072,1024]
    transpose_tile(w_in, w_in_t, 1024, 3072, blk - 4096, 96, tid);
  } else {  // w_out [1024,1024] -> [1024,1024]^T
    transpose_tile(w_out, w_out_t, 1024, 1024, blk - 7168, 32, tid);
  }
}

// ---------------- GEMM: C[M,N] = A[M,K=1024] * Bt[N,K]^T + bias ------------
// BK=64: 16 K-iters x 32 MFMA. LDS tiles 128x64, XOR-chunk-swizzled so
// global_load_lds (linear, wave-uniform-base) + conflict-free b128 reads.
// MODE 0: scatter bf16 into q/k [B,H,L,dh], v transposed [B,H,dh,L]
// MODE 1: fp32 out [M,1024]
template <int MODE>
__launch_bounds__(256, 3)
__global__ void k_gemm(const short* __restrict__ A, const short* __restrict__ Bt,
                       const float* __restrict__ bias, float* __restrict__ Cf,
                       short* __restrict__ qo, short* __restrict__ ko,
                       short* __restrict__ vo) {
  constexpr int KD = 1024;
  __shared__ __align__(16) short As[128 * 64];  // 16 KB
  __shared__ __align__(16) short Bs[128 * 64];  // 16 KB
  const int tid = threadIdx.x;
  const int wave = tid >> 6, lane = tid & 63;
  const int quad = lane >> 4, l16 = lane & 15;
  const int wm = wave >> 1, wn = wave & 1;
  const int tM = blockIdx.y * 128, tN = blockIdx.x * 128;

  const short* pA[4];
  const short* pB[4];
  short* lA[4];
  short* lB[4];
#pragma unroll
  for (int t = 0; t < 4; ++t) {
    const int c = t * 256 + tid;
    const int row = c >> 3, gch = (c & 7) ^ (row & 7);
    pA[t] = A + (size_t)(tM + row) * KD + gch * 8;
    pB[t] = Bt + (size_t)(tN + row) * KD + gch * 8;
    lA[t] = &As[c * 8];
    lB[t] = &Bs[c * 8];
  }

  const int sw = l16 & 7;
  const int col0 = (quad ^ sw) << 3;
  const int col1 = col0 ^ 32;

  f32x4 acc[4][4] = {};

  for (int k0 = 0; k0 < KD; k0 += 64) {
    __syncthreads();
#pragma unroll
    for (int t = 0; t < 4; ++t) {
      async16(pA[t] + k0, lA[t]);
      async16(pB[t] + k0, lB[t]);
    }
    __syncthreads();
#pragma unroll
    for (int kh = 0; kh < 2; ++kh) {
      const int col = kh ? col1 : col0;
      short8 af[4], bfr[4];
#pragma unroll
      for (int i = 0; i < 4; ++i)
        af[i] = *(const short8*)&As[(wm * 64 + i * 16 + l16) * 64 + col];
#pragma unroll
      for (int i = 0; i < 4; ++i)
        bfr[i] = *(const short8*)&Bs[(wn * 64 + i * 16 + l16) * 64 + col];
#pragma unroll
      for (int i = 0; i < 4; ++i)
#pragma unroll
        for (int j = 0; j < 4; ++j)
          acc[i][j] = __builtin_amdgcn_mfma_f32_16x16x32_bf16(af[i], bfr[j], acc[i][j], 0, 0, 0);
    }
  }

  const int rbase = tM + wm * 64 + quad * 4;
#pragma unroll
  for (int i = 0; i < 4; ++i) {
#pragma unroll
    for (int j = 0; j < 4; ++j) {
      const int col = tN + wn * 64 + j * 16 + l16;
      const float bi = bias[col];
      if (MODE == 0) {
        const int which = col >> 10;  // uniform per block
        const int h = (col & 1023) >> 6, d = col & 63;
        if (which == 2) {
          const int row0 = rbase + i * 16;
          const int b = row0 >> 11, li0 = row0 & 2047;
          f32x4 t;
#pragma unroll
          for (int rr = 0; rr < 4; ++rr) t[rr] = acc[i][j][rr] + bi;
          *(short4v*)&vo[(((size_t)(b * NH + h)) * DH + d) * SEQ + li0] = cvt4(t);
        } else {
          short* dst = (which == 0) ? qo : ko;
#pragma unroll
          for (int rr = 0; rr < 4; ++rr) {
            const int row = rbase + i * 16 + rr;
            const int b = row >> 11, li = row & 2047;
            dst[(((size_t)(b * NH + h)) * SEQ + li) * DH + d] = f2bf(acc[i][j][rr] + bi);
          }
        }
      } else {
#pragma unroll
        for (int rr = 0; rr < 4; ++rr) {
          const int row = rbase + i * 16 + rr;
          Cf[(size_t)row * DMODEL + col] = acc[i][j][rr] + bi;
        }
      }
    }
  }
}

// -------- flash attention, S^T orientation, fixed-max softmax --------------
// 1D grid 1024, true LPT: qt = 31-(bx>>5) (all 32 biggest blocks first),
// bh = bx&31. 4-5 resident blocks/CU; shrinking blocks fill the tail.
__launch_bounds__(256)
__global__ void k_attn(const short* __restrict__ q, const short* __restrict__ k,
                       const short* __restrict__ vt, short* __restrict__ o) {
  __shared__ __align__(16) short Qs[64 * 64];
  __shared__ __align__(16) short Ks[64 * 64];
  __shared__ __align__(16) short Vs[64 * 64];     // V^T tile [d][key]
  __shared__ __align__(16) short Ps[4][16 * 64];  // per-wave P [q][key]
  const int tid = threadIdx.x;
  const int wave = tid >> 6, lane = tid & 63;
  const int quad = lane >> 4, l16 = lane & 15;
  const int sw = l16 & 7;
  const int qt = 31 - (blockIdx.x >> 5);
  const int bh = blockIdx.x & 31;
  const int h = bh & (NH - 1);
  const size_t base = (size_t)bh * SEQ * DH;
  const float LOG2E = 1.44269504088896f;
  const float slope2 = exp2f(-0.5f * (float)(h + 1)) * LOG2E;  // slope*log2e
  const float scale2 = 0.125f * LOG2E;                         // (1/8)*log2e
  const float FM = 12.0f;  // fixed softmax max; cancels in O/l exactly

  const int c0i = tid, c1i = 256 + tid;
  const int r0 = c0i >> 3, ch0 = (c0i & 7) ^ (r0 & 7);
  const int r1 = c1i >> 3, ch1 = (c1i & 7) ^ (r1 & 7);
  const int qk_off0 = r0 * DH + ch0 * 8;
  const int qk_off1 = r1 * DH + ch1 * 8;
  const int v_off0 = r0 * SEQ + ch0 * 8;
  const int v_off1 = r1 * SEQ + ch1 * 8;
  short* lQ0 = &Qs[c0i * 8]; short* lQ1 = &Qs[c1i * 8];
  short* lK0 = &Ks[c0i * 8]; short* lK1 = &Ks[c1i * 8];
  short* lV0 = &Vs[c0i * 8]; short* lV1 = &Vs[c1i * 8];

  const int col0 = ((quad ^ sw) << 3);
  const int col1 = col0 ^ 32;
  int psoff[4];
#pragma unroll
  for (int in = 0; in < 4; ++in)
    psoff[in] = l16 * 64 + (((2 * in + (quad >> 1)) ^ sw) << 3) + (quad & 1) * 4;
  const int qlim4 = wave * 16 + l16 - 4 * quad;  // diag: keep 16*in+r <= qlim4
  const float s64 = slope2 * 64.0f;
  float rc[4];
#pragma unroll
  for (int r = 0; r < 4; ++r) rc[r] = slope2 * (float)r;

  const int q0 = qt * 64;
  {
    const short* qb = q + base + (size_t)q0 * DH;
    async16(qb + qk_off0, lQ0);
    async16(qb + qk_off1, lQ1);
  }
  __syncthreads();
  const short8 qb0 = *(const short8*)&Qs[(wave * 16 + l16) * 64 + col0];
  const short8 qb1 = *(const short8*)&Qs[(wave * 16 + l16) * 64 + col1];

  f32x4 accO[4] = {};
  float lsum = 0.f;
  const int qrow = q0 + wave * 16 + l16;  // each lane owns ONE q-row
  const float qoff = -slope2 * (float)qrow - FM + slope2 * (float)(4 * quad);
  float inoff[4];
#pragma unroll
  for (int in = 0; in < 4; ++in)
    inoff[in] = qoff + slope2 * (float)(16 * in);

  const short* kp = k + base;
  const short* vp = vt + base;
  for (int kt = 0; kt <= qt; ++kt) {
    __syncthreads();
    async16(kp + qk_off0, lK0);
    async16(kp + qk_off1, lK1);
    async16(vp + v_off0, lV0);
    async16(vp + v_off1, lV1);
    kp += 64 * DH;
    vp += 64;
    __syncthreads();

    // S^T = K Q^T : lane holds keys 16*in+4*quad+r for q-row l16
    f32x4 s[4];
#pragma unroll
    for (int in = 0; in < 4; ++in) {
      const short8 ka0 = *(const short8*)&Ks[(in * 16 + l16) * 64 + col0];
      const short8 ka1 = *(const short8*)&Ks[(in * 16 + l16) * 64 + col1];
      f32x4 t = {};
      t = __builtin_amdgcn_mfma_f32_16x16x32_bf16(ka0, qb0, t, 0, 0, 0);
      t = __builtin_amdgcn_mfma_f32_16x16x32_bf16(ka1, qb1, t, 0, 0, 0);
      s[in] = t;
    }

    if (kt == qt) {  // diagonal: causal mask
#pragma unroll
      for (int in = 0; in < 4; ++in) {
        f32x4 p;
#pragma unroll
        for (int r = 0; r < 4; ++r) {
          float val = fast_exp2(fmaf(s[in][r], scale2, inoff[in] + rc[r]));
          val = (16 * in + r <= qlim4) ? val : 0.f;
          p[r] = val;
          lsum += val;
        }
        *(short4v*)&Ps[wave][psoff[in]] = cvt4(p);
      }
    } else {
#pragma unroll
      for (int in = 0; in < 4; ++in) {
        f32x4 p;
#pragma unroll
        for (int r = 0; r < 4; ++r) {
          float val = fast_exp2(fmaf(s[in][r], scale2, inoff[in] + rc[r]));
          p[r] = val;
          lsum += val;
        }
        *(short4v*)&Ps[wave][psoff[in]] = cvt4(p);
      }
    }
#pragma unroll
    for (int in = 0; in < 4; ++in) inoff[in] += s64;

    // O^T += V^T P^T
    const short8 pa0 = *(const short8*)&Ps[wave][l16 * 64 + col0];
    const short8 pa1 = *(const short8*)&Ps[wave][l16 * 64 + col1];
#pragma unroll
    for (int i = 0; i < 4; ++i) {
      const short8 va0 = *(const short8*)&Vs[(i * 16 + l16) * 64 + col0];
      const short8 va1 = *(const short8*)&Vs[(i * 16 + l16) * 64 + col1];
      accO[i] = __builtin_amdgcn_mfma_f32_16x16x32_bf16(va0, pa0, accO[i], 0, 0, 0);
      accO[i] = __builtin_amdgcn_mfma_f32_16x16x32_bf16(va1, pa1, accO[i], 0, 0, 0);
    }
  }

  lsum += __shfl_xor(lsum, 16, 64);
  lsum += __shfl_xor(lsum, 32, 64);
  const float inv = 1.0f / lsum;

  const int b = bh >> 4;
  short* ob = o + ((((size_t)b * SEQ + qrow) * NH + h) * DH + 4 * quad);
#pragma unroll
  for (int i = 0; i < 4; ++i) {
    f32x4 t;
#pragma unroll
    for (int r = 0; r < 4; ++r) t[r] = accO[i][r] * inv;
    *(short4v*)&ob[16 * i] = cvt4(t);
  }
}

extern "C" void kernel_launch(void* const* d_in, const int* in_sizes, int n_in,
                              void* d_out, int out_size, void* d_ws, size_t ws_size,
                              hipStream_t stream) {
  const float* x = (const float*)d_in[0];      // [2,2048,1024]
  const float* w_in = (const float*)d_in[1];   // [1024,3072]
  const float* b_in = (const float*)d_in[2];   // [3072]
  const float* w_out = (const float*)d_in[3];  // [1024,1024]
  const float* b_out = (const float*)d_in[4];  // [1024]
  float* out = (float*)d_out;

  char* ws = (char*)d_ws;
  short* xb = (short*)(ws);                     // 8 MB  bf16 x
  short* w_in_t = (short*)(ws + (8u << 20));    // 6 MB  bf16 w_in^T [3072][1024]
  short* w_out_t = (short*)(ws + (14u << 20));  // 2 MB  bf16 w_out^T [1024][1024]
  short* qv = (short*)(ws + (16u << 20));       // 8 MB  [B,H,L,dh]
  short* kv = (short*)(ws + (24u << 20));       // 8 MB  [B,H,L,dh]
  short* vv = (short*)(ws + (32u << 20));       // 8 MB  [B,H,dh,L] (transposed)
  short* ao = (short*)(ws + (40u << 20));       // 8 MB  attn out [B,L,D] bf16

  k_prep<<<8192, 256, 0, stream>>>(x, xb, w_in, w_in_t, w_out, w_out_t);
  k_gemm<0><<<dim3(24, 32), 256, 0, stream>>>(xb, w_in_t, b_in, nullptr, qv, kv, vv);
  k_attn<<<1024, 256, 0, stream>>>(qv, kv, vv, ao);
  k_gemm<1><<<dim3(8, 32), 256, 0, stream>>>(ao, w_out_t, b_out, out, nullptr, nullptr, nullptr);
}